// Round 5
// baseline (108.863 us; speedup 1.0000x reference)
//
#include <hip/hip_runtime.h>

#define BB 512
#define SS 4096
#define NPOS (BB * SS)

#define PEN_BLOCKS BB            // one block per row
#define CE_BLOCKS 2048           // 4 positions per thread, exact cover
#define TOTAL_BLOCKS (PEN_BLOCKS + CE_BLOCKS)
#define THREADS 256

// padded LDS address: one pad word per 16 elements -> read lane-stride 17 (coprime w/ 32 banks)
__device__ __forceinline__ int padi(int x) { return x + (x >> 4); }

// ws layout (4-byte words):
//   [0 .. CE_BLOCKS)                        float ce partials
//   [CE_BLOCKS .. 2*CE_BLOCKS)              int   nz partials
//   [2*CE_BLOCKS .. 2*CE_BLOCKS+PEN_BLOCKS) int   pen partials

__device__ __forceinline__ float ce_pos(const float4& lo, const float4& hi, int t,
                                        const float4& wlo, const float4& whi) {
    float m = fmaxf(fmaxf(fmaxf(lo.x, lo.y), fmaxf(lo.z, lo.w)),
                    fmaxf(fmaxf(hi.x, hi.y), fmaxf(hi.z, hi.w)));
    float se = __expf(lo.x - m) + __expf(lo.y - m) + __expf(lo.z - m) + __expf(lo.w - m)
             + __expf(hi.x - m) + __expf(hi.y - m) + __expf(hi.z - m) + __expf(hi.w - m);
    const float lse = m + __logf(se);
    const float4 h  = (t & 4) ? hi : lo;
    const float vx  = (t & 2) ? ((t & 1) ? h.w : h.z) : ((t & 1) ? h.y : h.x);
    const float4 wh = (t & 4) ? whi : wlo;
    const float wv  = (t & 2) ? ((t & 1) ? wh.w : wh.z) : ((t & 1) ? wh.y : wh.x);
    return (vx - lse) * wv;
}

__global__ __launch_bounds__(THREADS) void fused_loss_kernel(
    const float* __restrict__ logits, const int* __restrict__ targets,
    const int* __restrict__ structs, const float* __restrict__ cw,
    float* __restrict__ ce_part, int* __restrict__ nz_part, int* __restrict__ pen_part)
{
    const int bid = blockIdx.x;
    const int wave = threadIdx.x >> 6;
    const int lane = threadIdx.x & 63;

    __shared__ int srow[SS + SS / 16];   // padded row staging (pen blocks only)
    __shared__ int s_tot[4];
    __shared__ int s_min[4];
    __shared__ int s_pat[4];
    __shared__ float s_ce[4];
    __shared__ int s_nz[4];

    if (bid < PEN_BLOCKS) {
        // ---- structural penalty: one block per row ----
        const int* s = structs + bid * SS;
        #pragma unroll
        for (int j = 0; j < 4; j++) {
            const int g = j * THREADS + threadIdx.x;       // int4 index, coalesced global
            const int4 v = ((const int4*)s)[g];
            const int a = 4 * g + (g >> 2);                 // 4g..4g+3 share one pad group
            srow[a] = v.x; srow[a + 1] = v.y; srow[a + 2] = v.z; srow[a + 3] = v.w;
        }
        __syncthreads();

        int run = 0, minp = 0, pat = 0;
        if (threadIdx.x < THREADS - 1) {
            // fast path: chunk + 3 lookahead in registers; all clamps are identity here
            const int pb = threadIdx.x * 17;
            int e[19];
            #pragma unroll
            for (int j = 0; j < 16; j++) e[j] = srow[pb + j];
            e[16] = srow[pb + 17];   // skip pad hole at pb+16
            e[17] = srow[pb + 18];
            e[18] = srow[pb + 19];
            #pragma unroll
            for (int k = 0; k < 16; k++) {
                const int v0 = e[k];
                const int lp = (v0 == 1);
                const int rp = (v0 == 2);
                if (lp) {
                    const int n1 = e[k + 1], n2 = e[k + 2], n3 = e[k + 3];
                    pat += 2 * (n1 == 2) + 3 * ((n1 == 3) & (n2 == 2))
                         + 4 * ((n1 == 3) & (n2 == 3) & (n3 == 2));
                }
                run += lp - rp;
                minp = min(minp, run);
            }
        } else {
            // last thread: exact stale-reuse clamps from the reference (i >= SS-16)
            const int base = (THREADS - 1) * 16;
            for (int k = 0; k < 16; k++) {
                const int i = base + k;
                const int v0 = srow[padi(i)];
                const int lp = (v0 == 1);
                const int rp = (v0 == 2);
                if (lp) {
                    const int a  = (srow[padi(min(i + 1, SS - 1))] == 2);
                    const int d1 = (srow[padi(min(i + 1, SS - 2))] == 3);
                    const int r2 = (srow[padi(min(i + 2, SS - 1))] == 2);
                    const int d2 = (srow[padi(min(i + 2, SS - 2))] == 3);
                    const int r3 = (srow[padi(min(i + 3, SS - 1))] == 2);
                    pat += 2 * a + 3 * (d1 & r2) + 4 * (d1 & d2 & r3);
                }
                run += lp - rp;
                minp = min(minp, run);
            }
        }

        // wave-level inclusive prefix of run (lane order == chunk order)
        int incl = run;
        #pragma unroll
        for (int sh = 1; sh < 64; sh <<= 1) {
            int n = __shfl_up(incl, sh, 64);
            if (lane >= sh) incl += n;
        }
        if (lane == 63) s_tot[wave] = incl;
        __syncthreads();
        int waveExcl = 0;
        #pragma unroll
        for (int w = 0; w < 4; w++) waveExcl += (w < wave) ? s_tot[w] : 0;
        const int excl = waveExcl + incl - run;
        int cand = excl + minp;          // global min-prefix candidate of this thread
        int patW = pat;
        #pragma unroll
        for (int sh = 32; sh; sh >>= 1) {
            cand = min(cand, __shfl_xor(cand, sh, 64));
            patW += __shfl_xor(patW, sh, 64);
        }
        if (lane == 0) { s_min[wave] = cand; s_pat[wave] = patW; }
        __syncthreads();
        if (threadIdx.x == 0) {
            const int Ptot = s_tot[0] + s_tot[1] + s_tot[2] + s_tot[3];
            const int minAll = min(min(s_min[0], s_min[1]), min(s_min[2], s_min[3]));
            const int patAll = s_pat[0] + s_pat[1] + s_pat[2] + s_pat[3];
            // minAll <= 0 always (empty prefix = 0); unmatched = -minAll
            pen_part[bid] = patAll + Ptot - 2 * minAll;
        }
    } else {
        // ---- weighted CE: 4 consecutive positions per thread, 9 loads in flight ----
        const int cbid = bid - PEN_BLOCKS;
        const int tid = cbid * THREADS + threadIdx.x;
        const float4* lg4 = (const float4*)logits;
        const float4 L0 = lg4[8 * tid + 0];
        const float4 L1 = lg4[8 * tid + 1];
        const float4 L2 = lg4[8 * tid + 2];
        const float4 L3 = lg4[8 * tid + 3];
        const float4 L4 = lg4[8 * tid + 4];
        const float4 L5 = lg4[8 * tid + 5];
        const float4 L6 = lg4[8 * tid + 6];
        const float4 L7 = lg4[8 * tid + 7];
        const int4 tt = ((const int4*)targets)[tid];
        const float4 wlo = ((const float4*)cw)[0];
        const float4 whi = ((const float4*)cw)[1];

        float ce = ce_pos(L0, L1, tt.x, wlo, whi) + ce_pos(L2, L3, tt.y, wlo, whi)
                 + ce_pos(L4, L5, tt.z, wlo, whi) + ce_pos(L6, L7, tt.w, wlo, whi);
        int nz = (tt.x != 0) + (tt.y != 0) + (tt.z != 0) + (tt.w != 0);

        #pragma unroll
        for (int sh = 32; sh; sh >>= 1) {
            ce += __shfl_xor(ce, sh, 64);
            nz += __shfl_xor(nz, sh, 64);
        }
        if (lane == 0) { s_ce[wave] = ce; s_nz[wave] = nz; }
        __syncthreads();
        if (threadIdx.x == 0) {
            ce_part[cbid] = s_ce[0] + s_ce[1] + s_ce[2] + s_ce[3];
            nz_part[cbid] = s_nz[0] + s_nz[1] + s_nz[2] + s_nz[3];
        }
    }
}

__global__ __launch_bounds__(THREADS) void finalize_kernel(
    const float* __restrict__ ce_part, const int* __restrict__ nz_part,
    const int* __restrict__ pen_part, float* __restrict__ out)
{
    const int t = threadIdx.x;
    const int wave = t >> 6;
    const int lane = t & 63;
    const float4* ce4 = (const float4*)ce_part;   // 512 float4
    const int4*   nz4 = (const int4*)nz_part;     // 512 int4
    const int4*   pn4 = (const int4*)pen_part;    // 128 int4

    const float4 c0 = ce4[t], c1 = ce4[t + THREADS];
    const int4   n0 = nz4[t], n1 = nz4[t + THREADS];
    float ce = c0.x + c0.y + c0.z + c0.w + c1.x + c1.y + c1.z + c1.w;
    int nz = n0.x + n0.y + n0.z + n0.w + n1.x + n1.y + n1.z + n1.w;
    int pen = 0;
    if (t < 128) {
        const int4 p = pn4[t];
        pen = p.x + p.y + p.z + p.w;
    }
    #pragma unroll
    for (int sh = 32; sh; sh >>= 1) {
        ce += __shfl_xor(ce, sh, 64);
        nz += __shfl_xor(nz, sh, 64);
        pen += __shfl_xor(pen, sh, 64);
    }
    __shared__ float s_ce[4];
    __shared__ int s_nz[4], s_pen[4];
    if (lane == 0) { s_ce[wave] = ce; s_nz[wave] = nz; s_pen[wave] = pen; }
    __syncthreads();
    if (t == 0) {
        const float ceAll = s_ce[0] + s_ce[1] + s_ce[2] + s_ce[3];
        const int nzAll = s_nz[0] + s_nz[1] + s_nz[2] + s_nz[3];
        const int penAll = s_pen[0] + s_pen[1] + s_pen[2] + s_pen[3];
        const float ce_loss = -ceAll / (float)NPOS;
        const float penalty = (float)penAll / (float)nzAll;  // mean_b(pen)/(nz/B)
        out[0] = ce_loss + 0.1f * penalty;
    }
}

extern "C" void kernel_launch(void* const* d_in, const int* in_sizes, int n_in,
                              void* d_out, int out_size, void* d_ws, size_t ws_size,
                              hipStream_t stream) {
    const float* logits  = (const float*)d_in[0];
    const int*   targets = (const int*)d_in[1];
    const int*   structs = (const int*)d_in[2];
    const float* cw      = (const float*)d_in[3];
    float* out = (float*)d_out;

    float* ce_part = (float*)d_ws;
    int*   nz_part = (int*)d_ws + CE_BLOCKS;
    int*   pen_part = (int*)d_ws + 2 * CE_BLOCKS;

    fused_loss_kernel<<<TOTAL_BLOCKS, THREADS, 0, stream>>>(
        logits, targets, structs, cw, ce_part, nz_part, pen_part);
    finalize_kernel<<<1, THREADS, 0, stream>>>(ce_part, nz_part, pen_part, out);
}

// Round 6
// 104.087 us; speedup vs baseline: 1.0459x; 1.0459x over previous
//
#include <hip/hip_runtime.h>

#define BB 512
#define SS 4096
#define NPOS (BB * SS)

#define PEN_BLOCKS BB            // one block per row
#define CE_BLOCKS 4096           // 2 positions per thread, exact cover (best-measured R4 config)
#define TOTAL_BLOCKS (PEN_BLOCKS + CE_BLOCKS)
#define THREADS 256

// padded LDS address: one pad word per 16 elements -> read lane-stride 17 (coprime w/ 32 banks)
__device__ __forceinline__ int padi(int x) { return x + (x >> 4); }

// ws layout (4-byte words):
//   [0 .. CE_BLOCKS)                        float ce partials
//   [CE_BLOCKS .. 2*CE_BLOCKS)              int   nz partials
//   [2*CE_BLOCKS .. 2*CE_BLOCKS+PEN_BLOCKS) int   pen partials

__device__ __forceinline__ float ce_pos(const float4& lo, const float4& hi, int t,
                                        const float4& wlo, const float4& whi) {
    float m = fmaxf(fmaxf(fmaxf(lo.x, lo.y), fmaxf(lo.z, lo.w)),
                    fmaxf(fmaxf(hi.x, hi.y), fmaxf(hi.z, hi.w)));
    float se = __expf(lo.x - m) + __expf(lo.y - m) + __expf(lo.z - m) + __expf(lo.w - m)
             + __expf(hi.x - m) + __expf(hi.y - m) + __expf(hi.z - m) + __expf(hi.w - m);
    const float lse = m + __logf(se);
    const float4 h  = (t & 4) ? hi : lo;
    const float vx  = (t & 2) ? ((t & 1) ? h.w : h.z) : ((t & 1) ? h.y : h.x);
    const float4 wh = (t & 4) ? whi : wlo;
    const float wv  = (t & 2) ? ((t & 1) ? wh.w : wh.z) : ((t & 1) ? wh.y : wh.x);
    return (vx - lse) * wv;
}

__global__ __launch_bounds__(THREADS) void fused_loss_kernel(
    const float* __restrict__ logits, const int* __restrict__ targets,
    const int* __restrict__ structs, const float* __restrict__ cw,
    float* __restrict__ ce_part, int* __restrict__ nz_part, int* __restrict__ pen_part)
{
    const int bid = blockIdx.x;
    const int wave = threadIdx.x >> 6;
    const int lane = threadIdx.x & 63;

    __shared__ int srow[SS + SS / 16];   // padded row staging (pen blocks only)
    __shared__ int s_tot[4];
    __shared__ int s_min[4];
    __shared__ int s_pat[4];
    __shared__ float s_ce[4];
    __shared__ int s_nz[4];

    if (bid < PEN_BLOCKS) {
        // ---- structural penalty: one block per row ----
        const int* s = structs + bid * SS;
        #pragma unroll
        for (int j = 0; j < 4; j++) {
            const int g = j * THREADS + threadIdx.x;       // int4 index, coalesced global
            const int4 v = ((const int4*)s)[g];
            const int a = 4 * g + (g >> 2);                 // 4g..4g+3 share one pad group
            srow[a] = v.x; srow[a + 1] = v.y; srow[a + 2] = v.z; srow[a + 3] = v.w;
        }
        __syncthreads();

        int run = 0, minp = 0, pat = 0;
        if (threadIdx.x < THREADS - 1) {
            // fast path: chunk + 3 lookahead in registers; all clamps are identity here
            const int pb = threadIdx.x * 17;
            int e[19];
            #pragma unroll
            for (int j = 0; j < 16; j++) e[j] = srow[pb + j];
            e[16] = srow[pb + 17];   // skip pad hole at pb+16
            e[17] = srow[pb + 18];
            e[18] = srow[pb + 19];
            #pragma unroll
            for (int k = 0; k < 16; k++) {
                const int v0 = e[k];
                const int lp = (v0 == 1);
                const int rp = (v0 == 2);
                if (lp) {
                    const int n1 = e[k + 1], n2 = e[k + 2], n3 = e[k + 3];
                    pat += 2 * (n1 == 2) + 3 * ((n1 == 3) & (n2 == 2))
                         + 4 * ((n1 == 3) & (n2 == 3) & (n3 == 2));
                }
                run += lp - rp;
                minp = min(minp, run);
            }
        } else {
            // last thread: exact stale-reuse clamps from the reference (i >= SS-16)
            const int base = (THREADS - 1) * 16;
            for (int k = 0; k < 16; k++) {
                const int i = base + k;
                const int v0 = srow[padi(i)];
                const int lp = (v0 == 1);
                const int rp = (v0 == 2);
                if (lp) {
                    const int a  = (srow[padi(min(i + 1, SS - 1))] == 2);
                    const int d1 = (srow[padi(min(i + 1, SS - 2))] == 3);
                    const int r2 = (srow[padi(min(i + 2, SS - 1))] == 2);
                    const int d2 = (srow[padi(min(i + 2, SS - 2))] == 3);
                    const int r3 = (srow[padi(min(i + 3, SS - 1))] == 2);
                    pat += 2 * a + 3 * (d1 & r2) + 4 * (d1 & d2 & r3);
                }
                run += lp - rp;
                minp = min(minp, run);
            }
        }

        // wave-level inclusive prefix of run (lane order == chunk order)
        int incl = run;
        #pragma unroll
        for (int sh = 1; sh < 64; sh <<= 1) {
            int n = __shfl_up(incl, sh, 64);
            if (lane >= sh) incl += n;
        }
        if (lane == 63) s_tot[wave] = incl;
        __syncthreads();
        int waveExcl = 0;
        #pragma unroll
        for (int w = 0; w < 4; w++) waveExcl += (w < wave) ? s_tot[w] : 0;
        const int excl = waveExcl + incl - run;
        int cand = excl + minp;          // global min-prefix candidate of this thread
        int patW = pat;
        #pragma unroll
        for (int sh = 32; sh; sh >>= 1) {
            cand = min(cand, __shfl_xor(cand, sh, 64));
            patW += __shfl_xor(patW, sh, 64);
        }
        if (lane == 0) { s_min[wave] = cand; s_pat[wave] = patW; }
        __syncthreads();
        if (threadIdx.x == 0) {
            const int Ptot = s_tot[0] + s_tot[1] + s_tot[2] + s_tot[3];
            const int minAll = min(min(s_min[0], s_min[1]), min(s_min[2], s_min[3]));
            const int patAll = s_pat[0] + s_pat[1] + s_pat[2] + s_pat[3];
            // minAll <= 0 always (empty prefix = 0); unmatched = -minAll
            pen_part[bid] = patAll + Ptot - 2 * minAll;
        }
    } else {
        // ---- weighted CE: 2 consecutive positions per thread, 5 loads in flight ----
        const int cbid = bid - PEN_BLOCKS;
        const int tid = cbid * THREADS + threadIdx.x;
        const float4* lg4 = (const float4*)logits;
        const float4 L0 = lg4[4 * tid + 0];
        const float4 L1 = lg4[4 * tid + 1];
        const float4 L2 = lg4[4 * tid + 2];
        const float4 L3 = lg4[4 * tid + 3];
        const int2 tt = ((const int2*)targets)[tid];
        const float4 wlo = ((const float4*)cw)[0];
        const float4 whi = ((const float4*)cw)[1];

        float ce = ce_pos(L0, L1, tt.x, wlo, whi) + ce_pos(L2, L3, tt.y, wlo, whi);
        int nz = (tt.x != 0) + (tt.y != 0);

        #pragma unroll
        for (int sh = 32; sh; sh >>= 1) {
            ce += __shfl_xor(ce, sh, 64);
            nz += __shfl_xor(nz, sh, 64);
        }
        if (lane == 0) { s_ce[wave] = ce; s_nz[wave] = nz; }
        __syncthreads();
        if (threadIdx.x == 0) {
            ce_part[cbid] = s_ce[0] + s_ce[1] + s_ce[2] + s_ce[3];
            nz_part[cbid] = s_nz[0] + s_nz[1] + s_nz[2] + s_nz[3];
        }
    }
}

__global__ __launch_bounds__(THREADS) void finalize_kernel(
    const float* __restrict__ ce_part, const int* __restrict__ nz_part,
    const int* __restrict__ pen_part, float* __restrict__ out)
{
    const int t = threadIdx.x;
    const int wave = t >> 6;
    const int lane = t & 63;
    const float4* ce4 = (const float4*)ce_part;   // 1024 float4
    const int4*   nz4 = (const int4*)nz_part;     // 1024 int4
    const int4*   pn4 = (const int4*)pen_part;    // 128 int4

    float ce = 0.f;
    int nz = 0;
    #pragma unroll
    for (int k = 0; k < 4; k++) {
        const float4 c = ce4[t + k * THREADS];
        const int4   n = nz4[t + k * THREADS];
        ce += c.x + c.y + c.z + c.w;
        nz += n.x + n.y + n.z + n.w;
    }
    int pen = 0;
    if (t < 128) {
        const int4 p = pn4[t];
        pen = p.x + p.y + p.z + p.w;
    }
    #pragma unroll
    for (int sh = 32; sh; sh >>= 1) {
        ce += __shfl_xor(ce, sh, 64);
        nz += __shfl_xor(nz, sh, 64);
        pen += __shfl_xor(pen, sh, 64);
    }
    __shared__ float s_ce[4];
    __shared__ int s_nz[4], s_pen[4];
    if (lane == 0) { s_ce[wave] = ce; s_nz[wave] = nz; s_pen[wave] = pen; }
    __syncthreads();
    if (t == 0) {
        const float ceAll = s_ce[0] + s_ce[1] + s_ce[2] + s_ce[3];
        const int nzAll = s_nz[0] + s_nz[1] + s_nz[2] + s_nz[3];
        const int penAll = s_pen[0] + s_pen[1] + s_pen[2] + s_pen[3];
        const float ce_loss = -ceAll / (float)NPOS;
        const float penalty = (float)penAll / (float)nzAll;  // mean_b(pen)/(nz/B)
        out[0] = ce_loss + 0.1f * penalty;
    }
}

extern "C" void kernel_launch(void* const* d_in, const int* in_sizes, int n_in,
                              void* d_out, int out_size, void* d_ws, size_t ws_size,
                              hipStream_t stream) {
    const float* logits  = (const float*)d_in[0];
    const int*   targets = (const int*)d_in[1];
    const int*   structs = (const int*)d_in[2];
    const float* cw      = (const float*)d_in[3];
    float* out = (float*)d_out;

    float* ce_part = (float*)d_ws;
    int*   nz_part = (int*)d_ws + CE_BLOCKS;
    int*   pen_part = (int*)d_ws + 2 * CE_BLOCKS;

    fused_loss_kernel<<<TOTAL_BLOCKS, THREADS, 0, stream>>>(
        logits, targets, structs, cw, ce_part, nz_part, pen_part);
    finalize_kernel<<<1, THREADS, 0, stream>>>(ce_part, nz_part, pen_part, out);
}